// Round 1
// baseline (242.638 us; speedup 1.0000x reference)
//
#include <hip/hip_runtime.h>

#define NL   4
#define NH   4
#define HD   64
#define CD   256
#define SQL  1024
#define BB   16

typedef _Float16 half8 __attribute__((ext_vector_type(8)));
typedef _Float16 half4 __attribute__((ext_vector_type(4)));
typedef _Float16 half2v __attribute__((ext_vector_type(2)));
typedef float    f32x4 __attribute__((ext_vector_type(4)));
typedef unsigned short u16x8 __attribute__((ext_vector_type(8)));

static __device__ __forceinline__ float bf2f(unsigned short u) {
    union { unsigned int i; float f; } v; v.i = ((unsigned int)u) << 16; return v.f;
}
static __device__ __forceinline__ unsigned short f2bf(float f) {
    union { float f; unsigned int i; } v; v.f = f;
    unsigned int u = v.i;
    return (unsigned short)((u + 0x7fffu + ((u >> 16) & 1u)) >> 16);
}

// inline dtype detect: 1 = inputs are packed bf16, 0 = f32. Uniform scalar loop.
static __device__ __forceinline__ int detect_flag(const void* win) {
    const unsigned int* w = (const unsigned int*)win;
    int cnt = 0;
#pragma unroll 1
    for (int i = 0; i < 64; i++) {
        unsigned int lo = w[i] & 0xFFFFu;
        int e = (int)((lo >> 7) & 0xFF);
        cnt += (e >= 96 && e <= 144) ? 1 : 0;
    }
    return cnt >= 48 ? 1 : 0;
}

// ---------- merged prep ----------
// x: (B,C,S)->(B,S,C) f16 row-major (gemm B-frags).
// kv: -> kaF / vtF in MFMA-A-FRAGMENT ORDER: per (layer*NH+h), per l-tile,
//     8 chunks of [64 lanes][8 halfs]; glds-compatible (uniform base + lane*16B).
// w: elementwise cvt.
__global__ __launch_bounds__(256) void prep_all(const void* __restrict__ xin,
                                                const void* __restrict__ win,
                                                const void* __restrict__ kvin,
                                                _Float16* __restrict__ x16,
                                                _Float16* __restrict__ w16,
                                                _Float16* __restrict__ kaF,
                                                _Float16* __restrict__ vtF) {
    __shared__ __align__(16) _Float16 tile[64][72];
    const int bi = blockIdx.x;
    const int t = threadIdx.x;
    const int isbf = detect_flag(win);

    if (bi < 1024) {
        // ---- prep_x: (B,C,S) -> (B,S,C) f16 ----
        const int st = bi & 15, ct = (bi >> 4) & 3, b = bi >> 6;
        const int r = t >> 2, seg = t & 3;
        const size_t base = ((size_t)(b * CD + ct * 64 + r)) * SQL + st * 64 + seg * 16;
        float v[16];
        if (isbf) {
            const unsigned short* src = (const unsigned short*)xin + base;
            u16x8 u0 = *(const u16x8*)(src);
            u16x8 u1 = *(const u16x8*)(src + 8);
#pragma unroll
            for (int j = 0; j < 8; j++) { v[j] = bf2f(u0[j]); v[8 + j] = bf2f(u1[j]); }
        } else {
            const float* src = (const float*)xin + base;
#pragma unroll
            for (int c = 0; c < 4; c++) {
                f32x4 a = *(const f32x4*)(src + c * 4);
#pragma unroll
                for (int j = 0; j < 4; j++) v[c * 4 + j] = a[j];
            }
        }
#pragma unroll
        for (int j = 0; j < 16; j++) tile[r][seg * 16 + j] = (_Float16)v[j];
        __syncthreads();
        half8 o0, o1;
#pragma unroll
        for (int j = 0; j < 8; j++) { o0[j] = tile[seg * 16 + j][r]; o1[j] = tile[seg * 16 + 8 + j][r]; }
        _Float16* dt = x16 + ((size_t)(b * SQL + st * 64 + r)) * CD + ct * 64 + seg * 16;
        *(half8*)(dt) = o0;
        *(half8*)(dt + 8) = o1;
    } else if (bi < 1280) {
        // ---- prep_kv -> fragment-ordered kaF / vtF ----
        const int j2 = bi - 1024;
        const int lt = j2 & 15, ih = j2 >> 4;
        const int r = t >> 2, seg = t & 3;
        const size_t base = ((size_t)(ih * SQL + lt * 64 + r)) * HD + seg * 16;
        float v[16];
        if (isbf) {
            const unsigned short* src = (const unsigned short*)kvin + base;
            u16x8 u0 = *(const u16x8*)(src);
            u16x8 u1 = *(const u16x8*)(src + 8);
#pragma unroll
            for (int j = 0; j < 8; j++) { v[j] = bf2f(u0[j]); v[8 + j] = bf2f(u1[j]); }
        } else {
            const float* src = (const float*)kvin + base;
#pragma unroll
            for (int c = 0; c < 4; c++) {
                f32x4 a = *(const f32x4*)(src + c * 4);
#pragma unroll
                for (int j = 0; j < 4; j++) v[c * 4 + j] = a[j];
            }
        }
#pragma unroll
        for (int j = 0; j < 16; j++) tile[r][seg * 16 + j] = (_Float16)v[j];
        __syncthreads();
        const int l = t & 63, l16 = l & 15, q = l >> 4;
        _Float16* kaB = kaF + ((size_t)ih << 16);
        _Float16* vtB = vtF + ((size_t)ih << 16);
#pragma unroll
        for (int it = 0; it < 2; it++) {
            const int c = (t >> 6) + it * 4;       // 0..7
            const int kd = c >> 1, msp = c & 1;
            half8 ok, ov;
#pragma unroll
            for (int j = 0; j < 4; j++) {
                ok[j]     = tile[msp * 32 + l16][kd * 16 + q * 4 + j];
                ok[4 + j] = tile[msp * 32 + 16 + l16][kd * 16 + q * 4 + j];
                ov[j]     = tile[kd * 16 + q * 4 + j][msp * 32 + l16];
                ov[4 + j] = tile[kd * 16 + q * 4 + j][msp * 32 + 16 + l16];
            }
            *(half8*)(kaB + ((lt * 8 + c) << 9) + l * 8) = ok;
            *(half8*)(vtB + ((lt * 8 + c) << 9) + l * 8) = ov;
        }
    } else {
        // ---- prep_w: elementwise cvt ----
        const int i = (bi - 1280) * 256 + t;
        const size_t base = (size_t)i * 8;
        half8 h;
        if (isbf) {
            u16x8 u = *(const u16x8*)((const unsigned short*)win + base);
#pragma unroll
            for (int j = 0; j < 8; j++) h[j] = (_Float16)bf2f(u[j]);
        } else {
            const float* p = (const float*)win + base;
            f32x4 a0 = *(const f32x4*)(p);
            f32x4 a1 = *(const f32x4*)(p + 4);
#pragma unroll
            for (int j = 0; j < 4; j++) { h[j] = (_Float16)a0[j]; h[4 + j] = (_Float16)a1[j]; }
        }
        *(half8*)(w16 + base) = h;
    }
}

// ---------- fused layer ----------
// R15 change: grid was 512 blocks (2/CU) -> occupancy GRID-limited at 16.7%,
// all pipes <35% busy (latency/barrier-bound). Now each wave owns 16 s-cols
// (nt dim dropped), block = 64 s-cols, grid (16 s-tiles, NH, BB) = 1024 blocks
// = 4 blocks/CU = 16 waves/CU, 4 independent barrier domains per CU so the
// per-lt glds-drain + ds_read-latency chain of one block hides under the MFMA
// phases of the other three. LDS 32 KB x 4 = 128 <= 160 KiB; launch_bounds
// (256,4) caps VGPR at 128 (was 60) to guarantee residency. KV staging per
// block unchanged (tile is s-independent): glds stages each tile ONCE per
// block from L2. Fragment order in LDS == glds lane*16B scatter; ds_read_b128
// at lane*16B is conflict-free. Register P^T, ones-A MFMA row-sum (now 4/lt),
// exp2 with log2e folded into q scale (all proven).
__global__ __launch_bounds__(256, 4) void layer_fused(const _Float16* __restrict__ xg,
                                                      _Float16* __restrict__ xout,
                                                      const _Float16* __restrict__ w16,
                                                      const _Float16* __restrict__ kaF,
                                                      const _Float16* __restrict__ vtF,
                                                      const void* __restrict__ win,
                                                      void* __restrict__ outp,
                                                      int L) {
    __shared__ __align__(16) _Float16 kvbuf[2][8192];   // [buf][16 chunks x 512 halfs]
    const int sb = blockIdx.x;
    const int h  = blockIdx.y;
    const int b  = blockIdx.z;
    const int t  = threadIdx.x;
    const int wv = t >> 6, lane = t & 63, l16 = lane & 15, quad = lane >> 4;
    const int s0 = sb * 64 + wv * 16;        // wave's 16 s-columns

    const _Float16* kaB = kaF + ((size_t)(L * NH + h) << 16);
    const _Float16* vtB = vtF + ((size_t)(L * NH + h) << 16);

    // stage l-tile lt into kvbuf[buf]: wave wv stages 4 of 16 chunks.
    // chunk c<8 = ka chunk c, c>=8 = vt chunk c-8.
    auto stage = [&](int lt, int buf) {
#pragma unroll
        for (int j = 0; j < 4; j++) {
            const int c = wv * 4 + j;
            const _Float16* src = (c < 8)
                ? kaB + (((lt * 8 + c) << 9))
                : vtB + (((lt * 8 + (c - 8)) << 9));
            __builtin_amdgcn_global_load_lds(
                (const __attribute__((address_space(1))) void*)(src + lane * 8),
                (__attribute__((address_space(3))) void*)(&kvbuf[buf][c * 512]),
                16, 0, 0);
        }
    };

    stage(0, 0);   // overlaps the gemm below

    // ---- gemm: q^T[d=64][s=16] for this head, registers only ----
    f32x4 gacc[4];
#pragma unroll
    for (int md = 0; md < 4; md++)
#pragma unroll
        for (int r = 0; r < 4; r++) gacc[md][r] = 0.0f;
    const _Float16* wb = w16 + ((size_t)L << 16) + ((size_t)(h * 64) << 8);
#pragma unroll
    for (int kk = 0; kk < 8; kk++) {
        half8 bx = *(const half8*)(xg + ((size_t)((b << 10) + s0 + l16) << 8) +
                                   kk * 32 + quad * 8);
#pragma unroll
        for (int md = 0; md < 4; md++) {
            half8 aw = *(const half8*)(wb + ((size_t)(md * 16 + l16) << 8) + kk * 32 + quad * 8);
            gacc[md] = __builtin_amdgcn_mfma_f32_16x16x32_f16(aw, bx, gacc[md], 0, 0, 0);
        }
    }
    // q scale: 1/sqrt(64) * log2(e)
    half4 qh[4];
#pragma unroll
    for (int md = 0; md < 4; md++)
#pragma unroll
        for (int r = 0; r < 4; r++)
            qh[md][r] = (_Float16)(gacc[md][r] * 0.180336880111120f);

    half4 ones4;
#pragma unroll
    for (int r = 0; r < 4; r++) ones4[r] = (_Float16)1.0f;

    f32x4 oacc[4];
    f32x4 osum;
#pragma unroll
    for (int md = 0; md < 4; md++)
#pragma unroll
        for (int r = 0; r < 4; r++) oacc[md][r] = 0.0f;
#pragma unroll
    for (int r = 0; r < 4; r++) osum[r] = 0.0f;

    __syncthreads();   // tile 0 staged (syncthreads drains glds)

#pragma unroll 1
    for (int lt = 0; lt < 16; lt++) {
        const int buf = lt & 1;
        if (lt + 1 < 16) stage(lt + 1, buf ^ 1);

        const _Float16* base = &kvbuf[buf][0];
        // conflict-free ds_read_b128 fragment loads
        half8 kab[8], vab[8];
#pragma unroll
        for (int c = 0; c < 8; c++)
            kab[c] = *(const half8*)(base + c * 512 + lane * 8);
#pragma unroll
        for (int c = 0; c < 8; c++)
            vab[c] = *(const half8*)(base + (8 + c) * 512 + lane * 8);

        // S^T = K . q^T : M=l 4x16, N=s 16, K=d in 4 steps of 16
        f32x4 stt[4];
#pragma unroll
        for (int ms = 0; ms < 4; ms++)
#pragma unroll
            for (int r = 0; r < 4; r++) stt[ms][r] = 0.0f;
#pragma unroll
        for (int kd = 0; kd < 4; kd++)
#pragma unroll
            for (int msp = 0; msp < 2; msp++) {
                half8 kk8 = kab[kd * 2 + msp];
                half4 lo = __builtin_shufflevector(kk8, kk8, 0, 1, 2, 3);
                half4 hi = __builtin_shufflevector(kk8, kk8, 4, 5, 6, 7);
                stt[msp * 2] = __builtin_amdgcn_mfma_f32_16x16x16f16(
                    lo, qh[kd], stt[msp * 2], 0, 0, 0);
                stt[msp * 2 + 1] = __builtin_amdgcn_mfma_f32_16x16x16f16(
                    hi, qh[kd], stt[msp * 2 + 1], 0, 0, 0);
            }

        // exp2 in-register -> P^T B-frags
        half4 pb[4];
#pragma unroll
        for (int ms = 0; ms < 4; ms++) {
            float e0 = __builtin_amdgcn_exp2f(stt[ms][0]);
            float e1 = __builtin_amdgcn_exp2f(stt[ms][1]);
            float e2 = __builtin_amdgcn_exp2f(stt[ms][2]);
            float e3 = __builtin_amdgcn_exp2f(stt[ms][3]);
            half2v p01 = __builtin_bit_cast(half2v, __builtin_amdgcn_cvt_pkrtz(e0, e1));
            half2v p23 = __builtin_bit_cast(half2v, __builtin_amdgcn_cvt_pkrtz(e2, e3));
            pb[ms] = __builtin_shufflevector(p01, p23, 0, 1, 2, 3);
        }

        // O^T += V^T . P^T ; row-sum tile on the MFMA pipe
#pragma unroll
        for (int ks = 0; ks < 4; ks++) {
            osum = __builtin_amdgcn_mfma_f32_16x16x16f16(ones4, pb[ks], osum, 0, 0, 0);
#pragma unroll
            for (int mdp = 0; mdp < 2; mdp++) {
                half8 vv8 = vab[ks * 2 + mdp];
                half4 lo = __builtin_shufflevector(vv8, vv8, 0, 1, 2, 3);
                half4 hi = __builtin_shufflevector(vv8, vv8, 4, 5, 6, 7);
                oacc[mdp * 2] = __builtin_amdgcn_mfma_f32_16x16x16f16(
                    lo, pb[ks], oacc[mdp * 2], 0, 0, 0);
                oacc[mdp * 2 + 1] = __builtin_amdgcn_mfma_f32_16x16x16f16(
                    hi, pb[ks], oacc[mdp * 2 + 1], 0, 0, 0);
            }
        }
        __syncthreads();   // drains next-tile glds; protects buf reuse
    }

    // ---- normalize + store (every row of osum tile == lsum[s]) ----
    const float inv = 1.0f / osum[0];
    const int s = s0 + l16;

    if (L < NL - 1) {
#pragma unroll
        for (int md = 0; md < 4; md++) {
            half4 hv;
#pragma unroll
            for (int r = 0; r < 4; r++) hv[r] = (_Float16)(oacc[md][r] * inv);
            *(half4*)(xout + (((size_t)((b << 10) + s)) << 8) + (h << 6) + md * 16 + quad * 4) = hv;
        }
    } else if (detect_flag(win)) {
#pragma unroll
        for (int md = 0; md < 4; md++) {
#pragma unroll
            for (int r = 0; r < 4; r++) {
                const int c = (h << 6) + md * 16 + quad * 4 + r;
                ((unsigned short*)outp)[(((size_t)(b * CD + c)) << 10) + s] =
                    f2bf(oacc[md][r] * inv);
            }
        }
    } else {
#pragma unroll
        for (int md = 0; md < 4; md++) {
#pragma unroll
            for (int r = 0; r < 4; r++) {
                const int c = (h << 6) + md * 16 + quad * 4 + r;
                ((float*)outp)[(((size_t)(b * CD + c)) << 10) + s] =
                    oacc[md][r] * inv;
            }
        }
    }
}

extern "C" void kernel_launch(void* const* d_in, const int* in_sizes, int n_in,
                              void* d_out, int out_size, void* d_ws, size_t ws_size,
                              hipStream_t stream) {
    const void* xin = d_in[0];
    // d_in[1] = length: used only for its shape (L=1024) — values irrelevant
    const void* win = d_in[2];
    const void* kvin = d_in[3];

    char* ws = (char*)d_ws;
    const size_t MB = 1u << 20;
    _Float16* xa  = (_Float16*)(ws);               // 8 MB  (B,S,C) f16
    _Float16* xb  = (_Float16*)(ws + 8 * MB);      // 8 MB  ping-pong
    _Float16* w16 = (_Float16*)(ws + 16 * MB);     // 0.5 MB
    _Float16* kaF = (_Float16*)(ws + 17 * MB);     // 2 MB  K fragment-order
    _Float16* vtF = (_Float16*)(ws + 19 * MB);     // 2 MB  V^T fragment-order

    prep_all<<<dim3(1024 + 256 + 128), 256, 0, stream>>>(xin, win, kvin, xa, w16, kaF, vtF);

    _Float16* cur = xa;
    _Float16* nxt = xb;
    for (int i = 0; i < NL; i++) {
        layer_fused<<<dim3(SQL / 64, NH, BB), 256, 0, stream>>>(cur, nxt, w16, kaF, vtF,
                                                                win, d_out, i);
        _Float16* tmp = cur; cur = nxt; nxt = tmp;
    }
}

// Round 2
// 234.392 us; speedup vs baseline: 1.0352x; 1.0352x over previous
//
#include <hip/hip_runtime.h>

#define NL   4
#define NH   4
#define HD   64
#define CD   256
#define SQL  1024
#define BB   16

typedef _Float16 half8 __attribute__((ext_vector_type(8)));
typedef _Float16 half4 __attribute__((ext_vector_type(4)));
typedef _Float16 half2v __attribute__((ext_vector_type(2)));
typedef float    f32x4 __attribute__((ext_vector_type(4)));
typedef unsigned short u16x8 __attribute__((ext_vector_type(8)));

static __device__ __forceinline__ float bf2f(unsigned short u) {
    union { unsigned int i; float f; } v; v.i = ((unsigned int)u) << 16; return v.f;
}
static __device__ __forceinline__ unsigned short f2bf(float f) {
    union { float f; unsigned int i; } v; v.f = f;
    unsigned int u = v.i;
    return (unsigned short)((u + 0x7fffu + ((u >> 16) & 1u)) >> 16);
}

// inline dtype detect: 1 = inputs are packed bf16, 0 = f32. Uniform scalar loop.
static __device__ __forceinline__ int detect_flag(const void* win) {
    const unsigned int* w = (const unsigned int*)win;
    int cnt = 0;
#pragma unroll 1
    for (int i = 0; i < 64; i++) {
        unsigned int lo = w[i] & 0xFFFFu;
        int e = (int)((lo >> 7) & 0xFF);
        cnt += (e >= 96 && e <= 144) ? 1 : 0;
    }
    return cnt >= 48 ? 1 : 0;
}

// ---------- merged prep ----------
// x: (B,C,S)->(B,S,C) f16 row-major (gemm B-frags).
// kv: -> kaF / vtF in MFMA-A-FRAGMENT ORDER: per (layer*NH+h), per l-tile,
//     8 chunks of [64 lanes][8 halfs]; glds-compatible (uniform base + lane*16B).
// w: elementwise cvt.
__global__ __launch_bounds__(256) void prep_all(const void* __restrict__ xin,
                                                const void* __restrict__ win,
                                                const void* __restrict__ kvin,
                                                _Float16* __restrict__ x16,
                                                _Float16* __restrict__ w16,
                                                _Float16* __restrict__ kaF,
                                                _Float16* __restrict__ vtF) {
    __shared__ __align__(16) _Float16 tile[64][72];
    const int bi = blockIdx.x;
    const int t = threadIdx.x;
    const int isbf = detect_flag(win);

    if (bi < 1024) {
        // ---- prep_x: (B,C,S) -> (B,S,C) f16 ----
        const int st = bi & 15, ct = (bi >> 4) & 3, b = bi >> 6;
        const int r = t >> 2, seg = t & 3;
        const size_t base = ((size_t)(b * CD + ct * 64 + r)) * SQL + st * 64 + seg * 16;
        float v[16];
        if (isbf) {
            const unsigned short* src = (const unsigned short*)xin + base;
            u16x8 u0 = *(const u16x8*)(src);
            u16x8 u1 = *(const u16x8*)(src + 8);
#pragma unroll
            for (int j = 0; j < 8; j++) { v[j] = bf2f(u0[j]); v[8 + j] = bf2f(u1[j]); }
        } else {
            const float* src = (const float*)xin + base;
#pragma unroll
            for (int c = 0; c < 4; c++) {
                f32x4 a = *(const f32x4*)(src + c * 4);
#pragma unroll
                for (int j = 0; j < 4; j++) v[c * 4 + j] = a[j];
            }
        }
#pragma unroll
        for (int j = 0; j < 16; j++) tile[r][seg * 16 + j] = (_Float16)v[j];
        __syncthreads();
        half8 o0, o1;
#pragma unroll
        for (int j = 0; j < 8; j++) { o0[j] = tile[seg * 16 + j][r]; o1[j] = tile[seg * 16 + 8 + j][r]; }
        _Float16* dt = x16 + ((size_t)(b * SQL + st * 64 + r)) * CD + ct * 64 + seg * 16;
        *(half8*)(dt) = o0;
        *(half8*)(dt + 8) = o1;
    } else if (bi < 1280) {
        // ---- prep_kv -> fragment-ordered kaF / vtF ----
        const int j2 = bi - 1024;
        const int lt = j2 & 15, ih = j2 >> 4;
        const int r = t >> 2, seg = t & 3;
        const size_t base = ((size_t)(ih * SQL + lt * 64 + r)) * HD + seg * 16;
        float v[16];
        if (isbf) {
            const unsigned short* src = (const unsigned short*)kvin + base;
            u16x8 u0 = *(const u16x8*)(src);
            u16x8 u1 = *(const u16x8*)(src + 8);
#pragma unroll
            for (int j = 0; j < 8; j++) { v[j] = bf2f(u0[j]); v[8 + j] = bf2f(u1[j]); }
        } else {
            const float* src = (const float*)kvin + base;
#pragma unroll
            for (int c = 0; c < 4; c++) {
                f32x4 a = *(const f32x4*)(src + c * 4);
#pragma unroll
                for (int j = 0; j < 4; j++) v[c * 4 + j] = a[j];
            }
        }
#pragma unroll
        for (int j = 0; j < 16; j++) tile[r][seg * 16 + j] = (_Float16)v[j];
        __syncthreads();
        const int l = t & 63, l16 = l & 15, q = l >> 4;
        _Float16* kaB = kaF + ((size_t)ih << 16);
        _Float16* vtB = vtF + ((size_t)ih << 16);
#pragma unroll
        for (int it = 0; it < 2; it++) {
            const int c = (t >> 6) + it * 4;       // 0..7
            const int kd = c >> 1, msp = c & 1;
            half8 ok, ov;
#pragma unroll
            for (int j = 0; j < 4; j++) {
                ok[j]     = tile[msp * 32 + l16][kd * 16 + q * 4 + j];
                ok[4 + j] = tile[msp * 32 + 16 + l16][kd * 16 + q * 4 + j];
                ov[j]     = tile[kd * 16 + q * 4 + j][msp * 32 + l16];
                ov[4 + j] = tile[kd * 16 + q * 4 + j][msp * 32 + 16 + l16];
            }
            *(half8*)(kaB + ((lt * 8 + c) << 9) + l * 8) = ok;
            *(half8*)(vtB + ((lt * 8 + c) << 9) + l * 8) = ov;
        }
    } else {
        // ---- prep_w: elementwise cvt ----
        const int i = (bi - 1280) * 256 + t;
        const size_t base = (size_t)i * 8;
        half8 h;
        if (isbf) {
            u16x8 u = *(const u16x8*)((const unsigned short*)win + base);
#pragma unroll
            for (int j = 0; j < 8; j++) h[j] = (_Float16)bf2f(u[j]);
        } else {
            const float* p = (const float*)win + base;
            f32x4 a0 = *(const f32x4*)(p);
            f32x4 a1 = *(const f32x4*)(p + 4);
#pragma unroll
            for (int j = 0; j < 4; j++) { h[j] = (_Float16)a0[j]; h[4 + j] = (_Float16)a1[j]; }
        }
        *(half8*)(w16 + base) = h;
    }
}

// ---------- fused layer ----------
// R16: R15's 2x blocks regressed (44->50.6 us): each wave reads the FULL 16 KB
// KV tile per lt, so halving s/wave doubled LDS-read + glds traffic into
// shared per-CU pipes. Root cause of the 44 us plateau is the per-lt
// __syncthreads() vmcnt(0) drain (depth-1 prefetch fully exposed 16x/block).
// Fix = T3/T4 counted-vmcnt pipeline (m201/m218: counted-vs-drain0 +38-73%):
//  - geometry back to 512 blocks, 32 s-cols/wave (best reuse measured)
//  - 3 LDS buffers (48 KB), depth-2 glds prefetch: prologue stages tiles 0,1;
//    iter t: s_waitcnt vmcnt(4)  (tile t done, tile t+1 STAYS IN FLIGHT),
//    raw s_barrier, stage tile t+2 into buf[(t+2)%3] (= buf freed by t-1:
//    safe — passing the barrier implies every wave issued its iter-t-1 MFMAs,
//    hence its ds_reads landed). Never vmcnt(0) in the loop (last iter only).
//  - sched_barrier(0) after the barrier pins ds_reads behind it.
//  - setprio(1) around MFMA clusters (T5, attn-structure: +4-7%).
//  - V-fragment ds_reads after QK^T so their latency hides under exp2.
__global__ __launch_bounds__(256, 2) void layer_fused(const _Float16* __restrict__ xg,
                                                      _Float16* __restrict__ xout,
                                                      const _Float16* __restrict__ w16,
                                                      const _Float16* __restrict__ kaF,
                                                      const _Float16* __restrict__ vtF,
                                                      const void* __restrict__ win,
                                                      void* __restrict__ outp,
                                                      int L) {
    __shared__ __align__(16) _Float16 kvbuf[3][8192];   // [buf][16 chunks x 512 halfs]
    const int sb = blockIdx.x;
    const int h  = blockIdx.y;
    const int b  = blockIdx.z;
    const int t  = threadIdx.x;
    const int wv = t >> 6, lane = t & 63, l16 = lane & 15, quad = lane >> 4;
    const int s0 = sb * 128 + wv * 32;        // wave's 32 s-columns

    const _Float16* kaB = kaF + ((size_t)(L * NH + h) << 16);
    const _Float16* vtB = vtF + ((size_t)(L * NH + h) << 16);

    // stage l-tile lt into kvbuf[buf]: wave wv stages 4 of 16 chunks.
    // chunk c<8 = ka chunk c, c>=8 = vt chunk c-8.
    auto stage = [&](int lt, int buf) {
#pragma unroll
        for (int j = 0; j < 4; j++) {
            const int c = wv * 4 + j;
            const _Float16* src = (c < 8)
                ? kaB + (((lt * 8 + c) << 9))
                : vtB + (((lt * 8 + (c - 8)) << 9));
            __builtin_amdgcn_global_load_lds(
                (const __attribute__((address_space(1))) void*)(src + lane * 8),
                (__attribute__((address_space(3))) void*)(&kvbuf[buf][c * 512]),
                16, 0, 0);
        }
    };

    stage(0, 0);   // overlaps the gemm below

    // ---- gemm: q^T[d=64][s=32] for this head, registers only ----
    f32x4 gacc[4][2];
#pragma unroll
    for (int md = 0; md < 4; md++)
#pragma unroll
        for (int nt = 0; nt < 2; nt++)
#pragma unroll
            for (int r = 0; r < 4; r++) gacc[md][nt][r] = 0.0f;
    const _Float16* wb = w16 + ((size_t)L << 16) + ((size_t)(h * 64) << 8);
#pragma unroll
    for (int kk = 0; kk < 8; kk++) {
        half8 bx[2];
#pragma unroll
        for (int nt = 0; nt < 2; nt++)
            bx[nt] = *(const half8*)(xg + ((size_t)((b << 10) + s0 + nt * 16 + l16) << 8) +
                                     kk * 32 + quad * 8);
#pragma unroll
        for (int md = 0; md < 4; md++) {
            half8 aw = *(const half8*)(wb + ((size_t)(md * 16 + l16) << 8) + kk * 32 + quad * 8);
            gacc[md][0] = __builtin_amdgcn_mfma_f32_16x16x32_f16(aw, bx[0], gacc[md][0], 0, 0, 0);
            gacc[md][1] = __builtin_amdgcn_mfma_f32_16x16x32_f16(aw, bx[1], gacc[md][1], 0, 0, 0);
        }
    }
    // q scale: 1/sqrt(64) * log2(e)
    half4 qh[4][2];
#pragma unroll
    for (int md = 0; md < 4; md++)
#pragma unroll
        for (int nt = 0; nt < 2; nt++)
#pragma unroll
            for (int r = 0; r < 4; r++)
                qh[md][nt][r] = (_Float16)(gacc[md][nt][r] * 0.180336880111120f);

    half4 ones4;
#pragma unroll
    for (int r = 0; r < 4; r++) ones4[r] = (_Float16)1.0f;

    f32x4 oacc[4][2];
    f32x4 osum[2];
#pragma unroll
    for (int md = 0; md < 4; md++)
#pragma unroll
        for (int nt = 0; nt < 2; nt++)
#pragma unroll
            for (int r = 0; r < 4; r++) oacc[md][nt][r] = 0.0f;
#pragma unroll
    for (int nt = 0; nt < 2; nt++)
#pragma unroll
        for (int r = 0; r < 4; r++) osum[nt][r] = 0.0f;

    stage(1, 1);   // second prefetch in flight before the loop

#pragma unroll 1
    for (int lt = 0; lt < 16; lt++) {
        // counted wait: everything older than the newest 4 glds (= tile lt+1)
        // is complete => tile lt is resident. Only the final iter drains.
        if (lt < 15) { asm volatile("s_waitcnt vmcnt(4)" ::: "memory"); }
        else         { asm volatile("s_waitcnt vmcnt(0)" ::: "memory"); }
        __builtin_amdgcn_s_barrier();
        __builtin_amdgcn_sched_barrier(0);
        if (lt + 2 < 16) stage(lt + 2, (lt + 2) % 3);

        const _Float16* base = &kvbuf[lt % 3][0];
        // conflict-free ds_read_b128 fragment loads (K first; V after QK^T)
        half8 kab[8];
#pragma unroll
        for (int c = 0; c < 8; c++)
            kab[c] = *(const half8*)(base + c * 512 + lane * 8);

        // S^T = K . q^T : M=l 4x16, N=s 2x16, K=d in 4 steps of 16
        f32x4 stt[4][2];
#pragma unroll
        for (int ms = 0; ms < 4; ms++)
#pragma unroll
            for (int nt = 0; nt < 2; nt++)
#pragma unroll
                for (int r = 0; r < 4; r++) stt[ms][nt][r] = 0.0f;
        __builtin_amdgcn_s_setprio(1);
#pragma unroll
        for (int kd = 0; kd < 4; kd++)
#pragma unroll
            for (int msp = 0; msp < 2; msp++) {
                half8 kk8 = kab[kd * 2 + msp];
                half4 lo = __builtin_shufflevector(kk8, kk8, 0, 1, 2, 3);
                half4 hi = __builtin_shufflevector(kk8, kk8, 4, 5, 6, 7);
#pragma unroll
                for (int nt = 0; nt < 2; nt++) {
                    stt[msp * 2][nt] = __builtin_amdgcn_mfma_f32_16x16x16f16(
                        lo, qh[kd][nt], stt[msp * 2][nt], 0, 0, 0);
                    stt[msp * 2 + 1][nt] = __builtin_amdgcn_mfma_f32_16x16x16f16(
                        hi, qh[kd][nt], stt[msp * 2 + 1][nt], 0, 0, 0);
                }
            }
        __builtin_amdgcn_s_setprio(0);

        half8 vab[8];
#pragma unroll
        for (int c = 0; c < 8; c++)
            vab[c] = *(const half8*)(base + (8 + c) * 512 + lane * 8);

        // exp2 in-register -> P^T B-frags (V reads in flight underneath)
        half4 pb[4][2];
#pragma unroll
        for (int ms = 0; ms < 4; ms++)
#pragma unroll
            for (int nt = 0; nt < 2; nt++) {
                float e0 = __builtin_amdgcn_exp2f(stt[ms][nt][0]);
                float e1 = __builtin_amdgcn_exp2f(stt[ms][nt][1]);
                float e2 = __builtin_amdgcn_exp2f(stt[ms][nt][2]);
                float e3 = __builtin_amdgcn_exp2f(stt[ms][nt][3]);
                half2v p01 = __builtin_bit_cast(half2v, __builtin_amdgcn_cvt_pkrtz(e0, e1));
                half2v p23 = __builtin_bit_cast(half2v, __builtin_amdgcn_cvt_pkrtz(e2, e3));
                pb[ms][nt] = __builtin_shufflevector(p01, p23, 0, 1, 2, 3);
            }

        // O^T += V^T . P^T ; row-sum tile on the MFMA pipe
        __builtin_amdgcn_s_setprio(1);
#pragma unroll
        for (int ks = 0; ks < 4; ks++) {
#pragma unroll
            for (int nt = 0; nt < 2; nt++)
                osum[nt] = __builtin_amdgcn_mfma_f32_16x16x16f16(
                    ones4, pb[ks][nt], osum[nt], 0, 0, 0);
#pragma unroll
            for (int mdp = 0; mdp < 2; mdp++) {
                half8 vv8 = vab[ks * 2 + mdp];
                half4 lo = __builtin_shufflevector(vv8, vv8, 0, 1, 2, 3);
                half4 hi = __builtin_shufflevector(vv8, vv8, 4, 5, 6, 7);
#pragma unroll
                for (int nt = 0; nt < 2; nt++) {
                    oacc[mdp * 2][nt] = __builtin_amdgcn_mfma_f32_16x16x16f16(
                        lo, pb[ks][nt], oacc[mdp * 2][nt], 0, 0, 0);
                    oacc[mdp * 2 + 1][nt] = __builtin_amdgcn_mfma_f32_16x16x16f16(
                        hi, pb[ks][nt], oacc[mdp * 2 + 1][nt], 0, 0, 0);
                }
            }
        }
        __builtin_amdgcn_s_setprio(0);
    }

    // ---- normalize + store (every row of osum tile == lsum[s]) ----
    float inv[2];
#pragma unroll
    for (int nt = 0; nt < 2; nt++) inv[nt] = 1.0f / osum[nt][0];

    if (L < NL - 1) {
#pragma unroll
        for (int md = 0; md < 4; md++)
#pragma unroll
            for (int nt = 0; nt < 2; nt++) {
                const int s = s0 + nt * 16 + l16;
                half4 hv;
#pragma unroll
                for (int r = 0; r < 4; r++) hv[r] = (_Float16)(oacc[md][nt][r] * inv[nt]);
                *(half4*)(xout + (((size_t)((b << 10) + s)) << 8) + (h << 6) + md * 16 + quad * 4) = hv;
            }
    } else if (detect_flag(win)) {
#pragma unroll
        for (int md = 0; md < 4; md++)
#pragma unroll
            for (int nt = 0; nt < 2; nt++) {
                const int s = s0 + nt * 16 + l16;
#pragma unroll
                for (int r = 0; r < 4; r++) {
                    const int c = (h << 6) + md * 16 + quad * 4 + r;
                    ((unsigned short*)outp)[(((size_t)(b * CD + c)) << 10) + s] =
                        f2bf(oacc[md][nt][r] * inv[nt]);
                }
            }
    } else {
#pragma unroll
        for (int md = 0; md < 4; md++)
#pragma unroll
            for (int nt = 0; nt < 2; nt++) {
                const int s = s0 + nt * 16 + l16;
#pragma unroll
                for (int r = 0; r < 4; r++) {
                    const int c = (h << 6) + md * 16 + quad * 4 + r;
                    ((float*)outp)[(((size_t)(b * CD + c)) << 10) + s] =
                        oacc[md][nt][r] * inv[nt];
                }
            }
    }
}

extern "C" void kernel_launch(void* const* d_in, const int* in_sizes, int n_in,
                              void* d_out, int out_size, void* d_ws, size_t ws_size,
                              hipStream_t stream) {
    const void* xin = d_in[0];
    // d_in[1] = length: used only for its shape (L=1024) — values irrelevant
    const void* win = d_in[2];
    const void* kvin = d_in[3];

    char* ws = (char*)d_ws;
    const size_t MB = 1u << 20;
    _Float16* xa  = (_Float16*)(ws);               // 8 MB  (B,S,C) f16
    _Float16* xb  = (_Float16*)(ws + 8 * MB);      // 8 MB  ping-pong
    _Float16* w16 = (_Float16*)(ws + 16 * MB);     // 0.5 MB
    _Float16* kaF = (_Float16*)(ws + 17 * MB);     // 2 MB  K fragment-order
    _Float16* vtF = (_Float16*)(ws + 19 * MB);     // 2 MB  V^T fragment-order

    prep_all<<<dim3(1024 + 256 + 128), 256, 0, stream>>>(xin, win, kvin, xa, w16, kaF, vtF);

    _Float16* cur = xa;
    _Float16* nxt = xb;
    for (int i = 0; i < NL; i++) {
        layer_fused<<<dim3(SQL / 128, NH, BB), 256, 0, stream>>>(cur, nxt, w16, kaF, vtF,
                                                                 win, d_out, i);
        _Float16* tmp = cur; cur = nxt; nxt = tmp;
    }
}

// Round 3
// 204.364 us; speedup vs baseline: 1.1873x; 1.1469x over previous
//
#include <hip/hip_runtime.h>

#define NL   4
#define NH   4
#define HD   64
#define CD   256
#define SQL  1024
#define BB   16

typedef _Float16 half8 __attribute__((ext_vector_type(8)));
typedef _Float16 half4 __attribute__((ext_vector_type(4)));
typedef _Float16 half2v __attribute__((ext_vector_type(2)));
typedef float    f32x4 __attribute__((ext_vector_type(4)));
typedef float    f32x16 __attribute__((ext_vector_type(16)));
typedef unsigned short u16x8 __attribute__((ext_vector_type(8)));
typedef unsigned int  uint4v __attribute__((ext_vector_type(4)));

static __device__ __forceinline__ float bf2f(unsigned short u) {
    union { unsigned int i; float f; } v; v.i = ((unsigned int)u) << 16; return v.f;
}
static __device__ __forceinline__ unsigned short f2bf(float f) {
    union { float f; unsigned int i; } v; v.f = f;
    unsigned int u = v.i;
    return (unsigned short)((u + 0x7fffu + ((u >> 16) & 1u)) >> 16);
}

// inline dtype detect: 1 = inputs are packed bf16, 0 = f32. Uniform scalar loop.
static __device__ __forceinline__ int detect_flag(const void* win) {
    const unsigned int* w = (const unsigned int*)win;
    int cnt = 0;
#pragma unroll 1
    for (int i = 0; i < 64; i++) {
        unsigned int lo = w[i] & 0xFFFFu;
        int e = (int)((lo >> 7) & 0xFF);
        cnt += (e >= 96 && e <= 144) ? 1 : 0;
    }
    return cnt >= 48 ? 1 : 0;
}

// ---------- merged prep ----------
// x: (B,C,S)->(B,S,C) f16 row-major (gemm B-frags).
// kv: -> kaF / vtF in 32x32x16 MFMA-A-FRAGMENT ORDER (R17): per (layer*NH+h),
//     per 64-l-tile, 8 chunks of [64 entries][8 halfs], glds-compatible.
//     ka chunk c=(lblk,kd16): entry(ln,hi) = K[lblk*32+ln][kd16*16+hi*8+j]
//     vt chunk c=(dblk,ks):   entry(ln,hi) = V[ks*16+hi*8+j][dblk*32+ln]
// w: elementwise cvt.
__global__ __launch_bounds__(256) void prep_all(const void* __restrict__ xin,
                                                const void* __restrict__ win,
                                                const void* __restrict__ kvin,
                                                _Float16* __restrict__ x16,
                                                _Float16* __restrict__ w16,
                                                _Float16* __restrict__ kaF,
                                                _Float16* __restrict__ vtF) {
    __shared__ __align__(16) _Float16 tile[64][72];
    const int bi = blockIdx.x;
    const int t = threadIdx.x;
    const int isbf = detect_flag(win);

    if (bi < 1024) {
        // ---- prep_x: (B,C,S) -> (B,S,C) f16 ----
        const int st = bi & 15, ct = (bi >> 4) & 3, b = bi >> 6;
        const int r = t >> 2, seg = t & 3;
        const size_t base = ((size_t)(b * CD + ct * 64 + r)) * SQL + st * 64 + seg * 16;
        float v[16];
        if (isbf) {
            const unsigned short* src = (const unsigned short*)xin + base;
            u16x8 u0 = *(const u16x8*)(src);
            u16x8 u1 = *(const u16x8*)(src + 8);
#pragma unroll
            for (int j = 0; j < 8; j++) { v[j] = bf2f(u0[j]); v[8 + j] = bf2f(u1[j]); }
        } else {
            const float* src = (const float*)xin + base;
#pragma unroll
            for (int c = 0; c < 4; c++) {
                f32x4 a = *(const f32x4*)(src + c * 4);
#pragma unroll
                for (int j = 0; j < 4; j++) v[c * 4 + j] = a[j];
            }
        }
#pragma unroll
        for (int j = 0; j < 16; j++) tile[r][seg * 16 + j] = (_Float16)v[j];
        __syncthreads();
        half8 o0, o1;
#pragma unroll
        for (int j = 0; j < 8; j++) { o0[j] = tile[seg * 16 + j][r]; o1[j] = tile[seg * 16 + 8 + j][r]; }
        _Float16* dt = x16 + ((size_t)(b * SQL + st * 64 + r)) * CD + ct * 64 + seg * 16;
        *(half8*)(dt) = o0;
        *(half8*)(dt + 8) = o1;
    } else if (bi < 1280) {
        // ---- prep_kv -> 32x32-fragment-ordered kaF / vtF ----
        const int j2 = bi - 1024;
        const int lt = j2 & 15, ih = j2 >> 4;
        const int r = t >> 2, seg = t & 3;
        const size_t base = ((size_t)(ih * SQL + lt * 64 + r)) * HD + seg * 16;
        float v[16];
        if (isbf) {
            const unsigned short* src = (const unsigned short*)kvin + base;
            u16x8 u0 = *(const u16x8*)(src);
            u16x8 u1 = *(const u16x8*)(src + 8);
#pragma unroll
            for (int j = 0; j < 8; j++) { v[j] = bf2f(u0[j]); v[8 + j] = bf2f(u1[j]); }
        } else {
            const float* src = (const float*)kvin + base;
#pragma unroll
            for (int c = 0; c < 4; c++) {
                f32x4 a = *(const f32x4*)(src + c * 4);
#pragma unroll
                for (int j = 0; j < 4; j++) v[c * 4 + j] = a[j];
            }
        }
#pragma unroll
        for (int j = 0; j < 16; j++) tile[r][seg * 16 + j] = (_Float16)v[j];
        __syncthreads();
        // tile[l_local][d]. Emit 32x32x16 A-frags.
        const int l = t & 63, hie = l >> 5, lne = l & 31;
        _Float16* kaB = kaF + ((size_t)ih << 16);
        _Float16* vtB = vtF + ((size_t)ih << 16);
#pragma unroll
        for (int it = 0; it < 2; it++) {
            const int c = (t >> 6) + it * 4;       // 0..7
            // ka: (lblk=c>>2, kd16=c&3): row=l=lblk*32+lne, k=d=kd16*16+hie*8+j
            half8 ok = *(const half8*)(&tile[(c >> 2) * 32 + lne][(c & 3) * 16 + hie * 8]);
            // vt: (dblk=c>>2, ks=c&3): row=d=dblk*32+lne, k=l=ks*16+hie*8+j
            half8 ov;
#pragma unroll
            for (int j = 0; j < 8; j++)
                ov[j] = tile[(c & 3) * 16 + hie * 8 + j][(c >> 2) * 32 + lne];
            *(half8*)(kaB + ((lt * 8 + c) << 9) + l * 8) = ok;
            *(half8*)(vtB + ((lt * 8 + c) << 9) + l * 8) = ov;
        }
    } else {
        // ---- prep_w: elementwise cvt ----
        const int i = (bi - 1280) * 256 + t;
        const size_t base = (size_t)i * 8;
        half8 h;
        if (isbf) {
            u16x8 u = *(const u16x8*)((const unsigned short*)win + base);
#pragma unroll
            for (int j = 0; j < 8; j++) h[j] = (_Float16)bf2f(u[j]);
        } else {
            const float* p = (const float*)win + base;
            f32x4 a0 = *(const f32x4*)(p);
            f32x4 a1 = *(const f32x4*)(p + 4);
#pragma unroll
            for (int j = 0; j < 4; j++) { h[j] = (_Float16)a0[j]; h[4 + j] = (_Float16)a1[j]; }
        }
        *(half8*)(w16 + base) = h;
    }
}

// ---------- fused layer (R17: full-rate 32x32x16 everywhere) ----------
// R16 post-mortem: counted-vmcnt pipeline was neutral (45.6 vs 44.0) -> glds
// latency was never exposed; kernel is SUM-of-pipes bound and the MFMA term
// dominates because 16x16x16_f16 issues at the SAME cycles as 16x16x32
// (back-computed ~15.7 cyc/SIMD from MfmaUtil): K=16 shapes are HALF-RATE.
// R17: everything at 32x32x16 full rate. With s = lane&31 (wave owns 32 s),
// the 32x32 C-layout (col=lane&31,row=4hi+r3+8q2) converts to the 32x32
// B-layout (col=lane&31,k=hi*8+j) with ONE v_permlane32_swap_b32 per dword
// pair (exchange is lane<->lane+32 at equal s):
//   B.d0,B.d2 = swap(u01,w01); B.d1,B.d3 = swap(u23,w23)
//   u = C-regs q2=2k1 (rows 4hi+r3), w = q2=2k1+1 (rows 8+4hi+r3).
// Used for: gemm-C -> QK B-frags (once) and exp(S^T) -> PV B-frags (per tile).
// MFMA/wave/64-l-tile: 8 QK + 8 PV (was 32+8+32 half-rate). Row-sum now VALU
// (32 adds) + final swap-add pair-combine. 128-l per barrier (2 sub-tiles,
// half the barriers), LDS 2x32KB, 2 blocks/CU.
__global__ __launch_bounds__(256, 2) void layer_fused(const _Float16* __restrict__ xg,
                                                      _Float16* __restrict__ xout,
                                                      const _Float16* __restrict__ w16,
                                                      const _Float16* __restrict__ kaF,
                                                      const _Float16* __restrict__ vtF,
                                                      const void* __restrict__ win,
                                                      void* __restrict__ outp,
                                                      int L) {
    __shared__ __align__(16) _Float16 kvbuf[2][16384];  // [buf][2 sub x 16 chunks x 512]
    const int sb = blockIdx.x;
    const int h  = blockIdx.y;
    const int b  = blockIdx.z;
    const int t  = threadIdx.x;
    const int wv = t >> 6, lane = t & 63, ln = lane & 31, hi = lane >> 5;
    const int s0 = sb * 128 + wv * 32;        // wave's 32 s-columns

    const _Float16* kaB = kaF + ((size_t)(L * NH + h) << 16);
    const _Float16* vtB = vtF + ((size_t)(L * NH + h) << 16);

    // stage 64-l-tile lt into kvbuf[buf] half hf: wave stages 4 of 16 chunks.
    auto stage = [&](int lt, int buf, int hf) {
#pragma unroll
        for (int j = 0; j < 4; j++) {
            const int c = wv * 4 + j;
            const _Float16* src = (c < 8)
                ? kaB + (((lt * 8 + c) << 9))
                : vtB + (((lt * 8 + (c - 8)) << 9));
            __builtin_amdgcn_global_load_lds(
                (const __attribute__((address_space(1))) void*)(src + lane * 8),
                (__attribute__((address_space(3))) void*)(&kvbuf[buf][hf * 8192 + c * 512]),
                16, 0, 0);
        }
    };

    stage(0, 0, 0);
    stage(1, 0, 1);   // overlap the gemm below

    // ---- gemm: q^T[d=64][s=32], 32x32x16, M=d 2x32, N=s=32, K=c 16x16 ----
    f32x16 gacc[2];
#pragma unroll
    for (int dblk = 0; dblk < 2; dblk++)
#pragma unroll
        for (int r = 0; r < 16; r++) gacc[dblk][r] = 0.0f;
    const _Float16* wb = w16 + ((size_t)L << 16) + ((size_t)(h * 64) << 8);
#pragma unroll
    for (int kc = 0; kc < 16; kc++) {
        half8 bx = *(const half8*)(xg + ((size_t)((b << 10) + s0 + ln) << 8) + kc * 16 + hi * 8);
#pragma unroll
        for (int dblk = 0; dblk < 2; dblk++) {
            half8 aw = *(const half8*)(wb + ((size_t)(dblk * 32 + ln) << 8) + kc * 16 + hi * 8);
            gacc[dblk] = __builtin_amdgcn_mfma_f32_32x32x16_f16(aw, bx, gacc[dblk], 0, 0, 0);
        }
    }

    // q C-tile -> QK B-frags (scale 1/8*log2e folded), 8 permlane swaps total
    const float sc = 0.180336880111120f;
    half8 qb[4];
#pragma unroll
    for (int dblk = 0; dblk < 2; dblk++)
#pragma unroll
        for (int k1 = 0; k1 < 2; k1++) {
            unsigned int u01 = __builtin_bit_cast(unsigned int,
                __builtin_amdgcn_cvt_pkrtz(gacc[dblk][k1 * 8 + 0] * sc, gacc[dblk][k1 * 8 + 1] * sc));
            unsigned int u23 = __builtin_bit_cast(unsigned int,
                __builtin_amdgcn_cvt_pkrtz(gacc[dblk][k1 * 8 + 2] * sc, gacc[dblk][k1 * 8 + 3] * sc));
            unsigned int w01 = __builtin_bit_cast(unsigned int,
                __builtin_amdgcn_cvt_pkrtz(gacc[dblk][k1 * 8 + 4] * sc, gacc[dblk][k1 * 8 + 5] * sc));
            unsigned int w23 = __builtin_bit_cast(unsigned int,
                __builtin_amdgcn_cvt_pkrtz(gacc[dblk][k1 * 8 + 6] * sc, gacc[dblk][k1 * 8 + 7] * sc));
            asm("v_permlane32_swap_b32 %0, %1" : "+v"(u01), "+v"(w01));
            asm("v_permlane32_swap_b32 %0, %1" : "+v"(u23), "+v"(w23));
            uint4v q; q[0] = u01; q[1] = u23; q[2] = w01; q[3] = w23;
            qb[dblk * 2 + k1] = __builtin_bit_cast(half8, q);
        }

    f32x16 oacc[2];
#pragma unroll
    for (int dblk = 0; dblk < 2; dblk++)
#pragma unroll
        for (int r = 0; r < 16; r++) oacc[dblk][r] = 0.0f;
    f32x4 rsum;
#pragma unroll
    for (int r = 0; r < 4; r++) rsum[r] = 0.0f;

    __syncthreads();   // tiles 0,1 staged

#pragma unroll 1
    for (int ltp = 0; ltp < 8; ltp++) {
        const int buf = ltp & 1;
        if (ltp < 7) { stage(2 * ltp + 2, buf ^ 1, 0); stage(2 * ltp + 3, buf ^ 1, 1); }
#pragma unroll
        for (int sub = 0; sub < 2; sub++) {
            const _Float16* base = &kvbuf[buf][sub * 8192];
            // conflict-free ds_read_b128 A-frag loads (K now; V after QK)
            half8 kab[8];
#pragma unroll
            for (int c = 0; c < 8; c++)
                kab[c] = *(const half8*)(base + c * 512 + lane * 8);

            // S^T = K . q^T : 2 l-blocks x K=d 4x16
            f32x16 stt[2];
#pragma unroll
            for (int lblk = 0; lblk < 2; lblk++)
#pragma unroll
                for (int r = 0; r < 16; r++) stt[lblk][r] = 0.0f;
            __builtin_amdgcn_s_setprio(1);
#pragma unroll
            for (int lblk = 0; lblk < 2; lblk++)
#pragma unroll
                for (int kd = 0; kd < 4; kd++)
                    stt[lblk] = __builtin_amdgcn_mfma_f32_32x32x16_f16(
                        kab[lblk * 4 + kd], qb[kd], stt[lblk], 0, 0, 0);
            __builtin_amdgcn_s_setprio(0);

            half8 vab[8];
#pragma unroll
            for (int c = 0; c < 8; c++)
                vab[c] = *(const half8*)(base + (8 + c) * 512 + lane * 8);

            // exp2 -> pack -> permlane swap -> P^T B-frags; VALU row-sum
            half8 pb[4];
#pragma unroll
            for (int lblk = 0; lblk < 2; lblk++) {
                float e[16];
#pragma unroll
                for (int r = 0; r < 16; r++) e[r] = __builtin_amdgcn_exp2f(stt[lblk][r]);
#pragma unroll
                for (int g = 0; g < 4; g++)
                    rsum[g] += (e[g * 4 + 0] + e[g * 4 + 1]) + (e[g * 4 + 2] + e[g * 4 + 3]);
#pragma unroll
                for (int k1 = 0; k1 < 2; k1++) {
                    unsigned int u01 = __builtin_bit_cast(unsigned int,
                        __builtin_amdgcn_cvt_pkrtz(e[k1 * 8 + 0], e[k1 * 8 + 1]));
                    unsigned int u23 = __builtin_bit_cast(unsigned int,
                        __builtin_amdgcn_cvt_pkrtz(e[k1 * 8 + 2], e[k1 * 8 + 3]));
                    unsigned int w01 = __builtin_bit_cast(unsigned int,
                        __builtin_amdgcn_cvt_pkrtz(e[k1 * 8 + 4], e[k1 * 8 + 5]));
                    unsigned int w23 = __builtin_bit_cast(unsigned int,
                        __builtin_amdgcn_cvt_pkrtz(e[k1 * 8 + 6], e[k1 * 8 + 7]));
                    asm("v_permlane32_swap_b32 %0, %1" : "+v"(u01), "+v"(w01));
                    asm("v_permlane32_swap_b32 %0, %1" : "+v"(u23), "+v"(w23));
                    uint4v p; p[0] = u01; p[1] = u23; p[2] = w01; p[3] = w23;
                    pb[lblk * 2 + k1] = __builtin_bit_cast(half8, p);
                }
            }

            // O^T += V^T . P^T : 2 d-blocks x K=l 4x16
            __builtin_amdgcn_s_setprio(1);
#pragma unroll
            for (int dblk = 0; dblk < 2; dblk++)
#pragma unroll
                for (int ks = 0; ks < 4; ks++)
                    oacc[dblk] = __builtin_amdgcn_mfma_f32_32x32x16_f16(
                        vab[dblk * 4 + ks], pb[ks], oacc[dblk], 0, 0, 0);
            __builtin_amdgcn_s_setprio(0);
        }
        __syncthreads();   // drains next-tile glds; protects buf reuse
    }

    // ---- denominator: pair-combine own+partner (lane<->lane+32) ----
    float rs = (rsum[0] + rsum[1]) + (rsum[2] + rsum[3]);
    unsigned int ra = __builtin_bit_cast(unsigned int, rs);
    unsigned int rb = ra;
    asm("" : "+v"(rb));   // force distinct register lineage
    asm("v_permlane32_swap_b32 %0, %1" : "+v"(ra), "+v"(rb));
    const float inv = 1.0f / (__builtin_bit_cast(float, ra) + __builtin_bit_cast(float, rb));
    const int s = s0 + ln;

    if (L < NL - 1) {
#pragma unroll
        for (int dblk = 0; dblk < 2; dblk++)
#pragma unroll
            for (int q2 = 0; q2 < 4; q2++) {
                half4 hv;
#pragma unroll
                for (int r = 0; r < 4; r++) hv[r] = (_Float16)(oacc[dblk][q2 * 4 + r] * inv);
                *(half4*)(xout + (((size_t)((b << 10) + s)) << 8) +
                          (h << 6) + dblk * 32 + q2 * 8 + hi * 4) = hv;
            }
    } else if (detect_flag(win)) {
#pragma unroll
        for (int dblk = 0; dblk < 2; dblk++)
#pragma unroll
            for (int q2 = 0; q2 < 4; q2++)
#pragma unroll
                for (int r = 0; r < 4; r++) {
                    const int c = (h << 6) + dblk * 32 + q2 * 8 + hi * 4 + r;
                    ((unsigned short*)outp)[(((size_t)(b * CD + c)) << 10) + s] =
                        f2bf(oacc[dblk][q2 * 4 + r] * inv);
                }
    } else {
#pragma unroll
        for (int dblk = 0; dblk < 2; dblk++)
#pragma unroll
            for (int q2 = 0; q2 < 4; q2++)
#pragma unroll
                for (int r = 0; r < 4; r++) {
                    const int c = (h << 6) + dblk * 32 + q2 * 8 + hi * 4 + r;
                    ((float*)outp)[(((size_t)(b * CD + c)) << 10) + s] =
                        oacc[dblk][q2 * 4 + r] * inv;
                }
    }
}

extern "C" void kernel_launch(void* const* d_in, const int* in_sizes, int n_in,
                              void* d_out, int out_size, void* d_ws, size_t ws_size,
                              hipStream_t stream) {
    const void* xin = d_in[0];
    // d_in[1] = length: used only for its shape (L=1024) — values irrelevant
    const void* win = d_in[2];
    const void* kvin = d_in[3];

    char* ws = (char*)d_ws;
    const size_t MB = 1u << 20;
    _Float16* xa  = (_Float16*)(ws);               // 8 MB  (B,S,C) f16
    _Float16* xb  = (_Float16*)(ws + 8 * MB);      // 8 MB  ping-pong
    _Float16* w16 = (_Float16*)(ws + 16 * MB);     // 0.5 MB
    _Float16* kaF = (_Float16*)(ws + 17 * MB);     // 2 MB  K fragment-order
    _Float16* vtF = (_Float16*)(ws + 19 * MB);     // 2 MB  V^T fragment-order

    prep_all<<<dim3(1024 + 256 + 128), 256, 0, stream>>>(xin, win, kvin, xa, w16, kaF, vtF);

    _Float16* cur = xa;
    _Float16* nxt = xb;
    for (int i = 0; i < NL; i++) {
        layer_fused<<<dim3(SQL / 128, NH, BB), 256, 0, stream>>>(cur, nxt, w16, kaF, vtF,
                                                                 win, d_out, i);
        _Float16* tmp = cur; cur = nxt; nxt = tmp;
    }
}

// Round 4
// 201.432 us; speedup vs baseline: 1.2046x; 1.0146x over previous
//
#include <hip/hip_runtime.h>

#define NL   4
#define NH   4
#define HD   64
#define CD   256
#define SQL  1024
#define BB   16

typedef _Float16 half8 __attribute__((ext_vector_type(8)));
typedef _Float16 half4 __attribute__((ext_vector_type(4)));
typedef _Float16 half2v __attribute__((ext_vector_type(2)));
typedef float    f32x4 __attribute__((ext_vector_type(4)));
typedef float    f32x16 __attribute__((ext_vector_type(16)));
typedef unsigned short u16x8 __attribute__((ext_vector_type(8)));
typedef unsigned int  uint4v __attribute__((ext_vector_type(4)));

static __device__ __forceinline__ float bf2f(unsigned short u) {
    union { unsigned int i; float f; } v; v.i = ((unsigned int)u) << 16; return v.f;
}
static __device__ __forceinline__ unsigned short f2bf(float f) {
    union { float f; unsigned int i; } v; v.f = f;
    unsigned int u = v.i;
    return (unsigned short)((u + 0x7fffu + ((u >> 16) & 1u)) >> 16);
}

// inline dtype detect: 1 = inputs are packed bf16, 0 = f32.
// R18: was a 64-deep SERIAL dependent-load chain (#pragma unroll 1 -> one
// outstanding load, ~300-800 cyc each = 5-20 us per block). Now 16 fully
// unrolled independent dwordx4 loads -> single waitcnt, ~1 us.
static __device__ __forceinline__ int detect_flag(const void* win) {
    const uint4v* w = (const uint4v*)win;
    int cnt = 0;
    uint4v u[16];
#pragma unroll
    for (int i = 0; i < 16; i++) u[i] = w[i];
#pragma unroll
    for (int i = 0; i < 16; i++)
#pragma unroll
        for (int j = 0; j < 4; j++) {
            unsigned int lo = u[i][j] & 0xFFFFu;
            int e = (int)((lo >> 7) & 0xFF);
            cnt += (e >= 96 && e <= 144) ? 1 : 0;
        }
    return cnt >= 48 ? 1 : 0;
}

// ---------- merged prep ----------
// x: (B,C,S)->(B,S,C) f16 row-major (gemm B-frags).
// kv: -> kaF / vtF in 32x32x16 MFMA-A-FRAGMENT ORDER: per (layer*NH+h),
//     per 64-l-tile, 8 chunks of [64 entries][8 halfs], glds-compatible.
//     ka chunk c=(lblk,kd16): entry(ln,hi) = K[lblk*32+ln][kd16*16+hi*8+j]
//     vt chunk c=(dblk,ks):   entry(ln,hi) = V[ks*16+hi*8+j][dblk*32+ln]
// w: elementwise cvt. Also publishes the dtype flag to *flagp (read by the
// last layer instead of re-running detect per block).
__global__ __launch_bounds__(256) void prep_all(const void* __restrict__ xin,
                                                const void* __restrict__ win,
                                                const void* __restrict__ kvin,
                                                _Float16* __restrict__ x16,
                                                _Float16* __restrict__ w16,
                                                _Float16* __restrict__ kaF,
                                                _Float16* __restrict__ vtF,
                                                int* __restrict__ flagp) {
    __shared__ __align__(16) _Float16 tile[64][72];
    const int bi = blockIdx.x;
    const int t = threadIdx.x;
    const int isbf = detect_flag(win);

    if (bi < 1024) {
        // ---- prep_x: (B,C,S) -> (B,S,C) f16 ----
        const int st = bi & 15, ct = (bi >> 4) & 3, b = bi >> 6;
        const int r = t >> 2, seg = t & 3;
        const size_t base = ((size_t)(b * CD + ct * 64 + r)) * SQL + st * 64 + seg * 16;
        float v[16];
        if (isbf) {
            const unsigned short* src = (const unsigned short*)xin + base;
            u16x8 u0 = *(const u16x8*)(src);
            u16x8 u1 = *(const u16x8*)(src + 8);
#pragma unroll
            for (int j = 0; j < 8; j++) { v[j] = bf2f(u0[j]); v[8 + j] = bf2f(u1[j]); }
        } else {
            const float* src = (const float*)xin + base;
#pragma unroll
            for (int c = 0; c < 4; c++) {
                f32x4 a = *(const f32x4*)(src + c * 4);
#pragma unroll
                for (int j = 0; j < 4; j++) v[c * 4 + j] = a[j];
            }
        }
#pragma unroll
        for (int j = 0; j < 16; j++) tile[r][seg * 16 + j] = (_Float16)v[j];
        __syncthreads();
        half8 o0, o1;
#pragma unroll
        for (int j = 0; j < 8; j++) { o0[j] = tile[seg * 16 + j][r]; o1[j] = tile[seg * 16 + 8 + j][r]; }
        _Float16* dt = x16 + ((size_t)(b * SQL + st * 64 + r)) * CD + ct * 64 + seg * 16;
        *(half8*)(dt) = o0;
        *(half8*)(dt + 8) = o1;
    } else if (bi < 1280) {
        // ---- prep_kv -> 32x32-fragment-ordered kaF / vtF ----
        const int j2 = bi - 1024;
        const int lt = j2 & 15, ih = j2 >> 4;
        const int r = t >> 2, seg = t & 3;
        const size_t base = ((size_t)(ih * SQL + lt * 64 + r)) * HD + seg * 16;
        float v[16];
        if (isbf) {
            const unsigned short* src = (const unsigned short*)kvin + base;
            u16x8 u0 = *(const u16x8*)(src);
            u16x8 u1 = *(const u16x8*)(src + 8);
#pragma unroll
            for (int j = 0; j < 8; j++) { v[j] = bf2f(u0[j]); v[8 + j] = bf2f(u1[j]); }
        } else {
            const float* src = (const float*)kvin + base;
#pragma unroll
            for (int c = 0; c < 4; c++) {
                f32x4 a = *(const f32x4*)(src + c * 4);
#pragma unroll
                for (int j = 0; j < 4; j++) v[c * 4 + j] = a[j];
            }
        }
#pragma unroll
        for (int j = 0; j < 16; j++) tile[r][seg * 16 + j] = (_Float16)v[j];
        __syncthreads();
        // tile[l_local][d]. Emit 32x32x16 A-frags.
        const int l = t & 63, hie = l >> 5, lne = l & 31;
        _Float16* kaB = kaF + ((size_t)ih << 16);
        _Float16* vtB = vtF + ((size_t)ih << 16);
#pragma unroll
        for (int it = 0; it < 2; it++) {
            const int c = (t >> 6) + it * 4;       // 0..7
            // ka: (lblk=c>>2, kd16=c&3): row=l=lblk*32+lne, k=d=kd16*16+hie*8+j
            half8 ok = *(const half8*)(&tile[(c >> 2) * 32 + lne][(c & 3) * 16 + hie * 8]);
            // vt: (dblk=c>>2, ks=c&3): row=d=dblk*32+lne, k=l=ks*16+hie*8+j
            half8 ov;
#pragma unroll
            for (int j = 0; j < 8; j++)
                ov[j] = tile[(c & 3) * 16 + hie * 8 + j][(c >> 2) * 32 + lne];
            *(half8*)(kaB + ((lt * 8 + c) << 9) + l * 8) = ok;
            *(half8*)(vtB + ((lt * 8 + c) << 9) + l * 8) = ov;
        }
    } else {
        // ---- prep_w: elementwise cvt (+ flag publish) ----
        if (bi == 1280 && t == 0) *flagp = isbf;
        const int i = (bi - 1280) * 256 + t;
        const size_t base = (size_t)i * 8;
        half8 h;
        if (isbf) {
            u16x8 u = *(const u16x8*)((const unsigned short*)win + base);
#pragma unroll
            for (int j = 0; j < 8; j++) h[j] = (_Float16)bf2f(u[j]);
        } else {
            const float* p = (const float*)win + base;
            f32x4 a0 = *(const f32x4*)(p);
            f32x4 a1 = *(const f32x4*)(p + 4);
#pragma unroll
            for (int j = 0; j < 4; j++) { h[j] = (_Float16)a0[j]; h[4 + j] = (_Float16)a1[j]; }
        }
        *(half8*)(w16 + base) = h;
    }
}

// ---------- fused layer (R18: phase-interleaved region body) ----------
// R17 post-mortem: halving MFMA cycles bought almost exactly the MFMA time
// -> pipes were SERIAL. Each barrier region ran [LDS burst][QK][exp][PV] in
// lockstep across all 8 waves/CU: four pipes, four phases, ~zero overlap.
// R18 reorders each region so every VALU phase is adjacent to an INDEPENDENT
// MFMA cluster and ds_reads issue under matrix-pipe time:
//   kabA,kabB -> QK_A -> vabA -> QK_B -> exp_A -> vabB -> PV_A -> exp_B -> PV_B
// (A/B = the region's two 64-l sub-tiles; per-wave parity sb^h^b^wv
// decorrelates co-resident blocks/waves). The in-order wave now issues
// MFMA clusters (1-cyc issues, async 32-cyc pipe) and keeps VALU busy
// underneath; 2 waves/SIMD fill the rest. Barrier/staging structure (proven
// neutral-cost in R16) unchanged: dbuf 2x32KB, stage-next at region top,
// __syncthreads at region end. Row-sum on VALU; exp2 with log2e folded into
// q scale; permlane32_swap C->B fragment conversion (all proven).
__global__ __launch_bounds__(256, 2) void layer_fused(const _Float16* __restrict__ xg,
                                                      _Float16* __restrict__ xout,
                                                      const _Float16* __restrict__ w16,
                                                      const _Float16* __restrict__ kaF,
                                                      const _Float16* __restrict__ vtF,
                                                      const int* __restrict__ flagp,
                                                      void* __restrict__ outp,
                                                      int L) {
    __shared__ __align__(16) _Float16 kvbuf[2][16384];  // [buf][2 sub x 16 chunks x 512]
    const int sb = blockIdx.x;
    const int h  = blockIdx.y;
    const int b  = blockIdx.z;
    const int t  = threadIdx.x;
    const int wv = t >> 6, lane = t & 63, ln = lane & 31, hi = lane >> 5;
    const int s0 = sb * 128 + wv * 32;        // wave's 32 s-columns
    const int par = (sb ^ h ^ b ^ wv) & 1;    // region sub-tile order A/B

    // last layer needs the dtype flag for the output store; single uniform load
    const int isbf_final = (L == NL - 1) ? *flagp : 0;

    const _Float16* kaB = kaF + ((size_t)(L * NH + h) << 16);
    const _Float16* vtB = vtF + ((size_t)(L * NH + h) << 16);

    // stage 64-l-tile lt into kvbuf[buf] half hf: wave stages 4 of 16 chunks.
    auto stage = [&](int lt, int buf, int hf) {
#pragma unroll
        for (int j = 0; j < 4; j++) {
            const int c = wv * 4 + j;
            const _Float16* src = (c < 8)
                ? kaB + (((lt * 8 + c) << 9))
                : vtB + (((lt * 8 + (c - 8)) << 9));
            __builtin_amdgcn_global_load_lds(
                (const __attribute__((address_space(1))) void*)(src + lane * 8),
                (__attribute__((address_space(3))) void*)(&kvbuf[buf][hf * 8192 + c * 512]),
                16, 0, 0);
        }
    };

    stage(0, 0, 0);
    stage(1, 0, 1);   // overlap the gemm below

    // ---- gemm: q^T[d=64][s=32], 32x32x16, M=d 2x32, N=s=32, K=c 16x16 ----
    f32x16 gacc[2];
#pragma unroll
    for (int dblk = 0; dblk < 2; dblk++)
#pragma unroll
        for (int r = 0; r < 16; r++) gacc[dblk][r] = 0.0f;
    const _Float16* wb = w16 + ((size_t)L << 16) + ((size_t)(h * 64) << 8);
#pragma unroll
    for (int kc = 0; kc < 16; kc++) {
        half8 bx = *(const half8*)(xg + ((size_t)((b << 10) + s0 + ln) << 8) + kc * 16 + hi * 8);
#pragma unroll
        for (int dblk = 0; dblk < 2; dblk++) {
            half8 aw = *(const half8*)(wb + ((size_t)(dblk * 32 + ln) << 8) + kc * 16 + hi * 8);
            gacc[dblk] = __builtin_amdgcn_mfma_f32_32x32x16_f16(aw, bx, gacc[dblk], 0, 0, 0);
        }
    }

    // q C-tile -> QK B-frags (scale 1/8*log2e folded), 8 permlane swaps total
    const float sc = 0.180336880111120f;
    half8 qb[4];
#pragma unroll
    for (int dblk = 0; dblk < 2; dblk++)
#pragma unroll
        for (int k1 = 0; k1 < 2; k1++) {
            unsigned int u01 = __builtin_bit_cast(unsigned int,
                __builtin_amdgcn_cvt_pkrtz(gacc[dblk][k1 * 8 + 0] * sc, gacc[dblk][k1 * 8 + 1] * sc));
            unsigned int u23 = __builtin_bit_cast(unsigned int,
                __builtin_amdgcn_cvt_pkrtz(gacc[dblk][k1 * 8 + 2] * sc, gacc[dblk][k1 * 8 + 3] * sc));
            unsigned int w01 = __builtin_bit_cast(unsigned int,
                __builtin_amdgcn_cvt_pkrtz(gacc[dblk][k1 * 8 + 4] * sc, gacc[dblk][k1 * 8 + 5] * sc));
            unsigned int w23 = __builtin_bit_cast(unsigned int,
                __builtin_amdgcn_cvt_pkrtz(gacc[dblk][k1 * 8 + 6] * sc, gacc[dblk][k1 * 8 + 7] * sc));
            asm("v_permlane32_swap_b32 %0, %1" : "+v"(u01), "+v"(w01));
            asm("v_permlane32_swap_b32 %0, %1" : "+v"(u23), "+v"(w23));
            uint4v q; q[0] = u01; q[1] = u23; q[2] = w01; q[3] = w23;
            qb[dblk * 2 + k1] = __builtin_bit_cast(half8, q);
        }

    f32x16 oacc[2];
#pragma unroll
    for (int dblk = 0; dblk < 2; dblk++)
#pragma unroll
        for (int r = 0; r < 16; r++) oacc[dblk][r] = 0.0f;
    f32x4 rsum;
#pragma unroll
    for (int r = 0; r < 4; r++) rsum[r] = 0.0f;

    __syncthreads();   // tiles 0,1 staged

#pragma unroll 1
    for (int ltp = 0; ltp < 8; ltp++) {
        const int buf = ltp & 1;
        if (ltp < 7) { stage(2 * ltp + 2, buf ^ 1, 0); stage(2 * ltp + 3, buf ^ 1, 1); }

        const _Float16* baseA = &kvbuf[buf][par * 8192];
        const _Float16* baseB = &kvbuf[buf][(par ^ 1) * 8192];

        // K A-frags for BOTH subs up front (issued under matrix-pipe time)
        half8 kabA[8], kabB[8];
#pragma unroll
        for (int c = 0; c < 8; c++) kabA[c] = *(const half8*)(baseA + c * 512 + lane * 8);
#pragma unroll
        for (int c = 0; c < 8; c++) kabB[c] = *(const half8*)(baseB + c * 512 + lane * 8);

        f32x16 sttA[2], sttB[2];
#pragma unroll
        for (int lblk = 0; lblk < 2; lblk++)
#pragma unroll
            for (int r = 0; r < 16; r++) { sttA[lblk][r] = 0.0f; sttB[lblk][r] = 0.0f; }

        // QK_A
        __builtin_amdgcn_s_setprio(1);
#pragma unroll
        for (int lblk = 0; lblk < 2; lblk++)
#pragma unroll
            for (int kd = 0; kd < 4; kd++)
                sttA[lblk] = __builtin_amdgcn_mfma_f32_32x32x16_f16(
                    kabA[lblk * 4 + kd], qb[kd], sttA[lblk], 0, 0, 0);
        __builtin_amdgcn_s_setprio(0);

        half8 vabA[8];
#pragma unroll
        for (int c = 0; c < 8; c++) vabA[c] = *(const half8*)(baseA + (8 + c) * 512 + lane * 8);

        // QK_B (independent of exp_A below: scheduler/pipe overlap)
        __builtin_amdgcn_s_setprio(1);
#pragma unroll
        for (int lblk = 0; lblk < 2; lblk++)
#pragma unroll
            for (int kd = 0; kd < 4; kd++)
                sttB[lblk] = __builtin_amdgcn_mfma_f32_32x32x16_f16(
                    kabB[lblk * 4 + kd], qb[kd], sttB[lblk], 0, 0, 0);
        __builtin_amdgcn_s_setprio(0);

        // exp_A -> pbA (VALU runs while QK_B drains the matrix pipe)
        half8 pbA[4];
#pragma unroll
        for (int lblk = 0; lblk < 2; lblk++) {
            float e[16];
#pragma unroll
            for (int r = 0; r < 16; r++) e[r] = __builtin_amdgcn_exp2f(sttA[lblk][r]);
#pragma unroll
            for (int g = 0; g < 4; g++)
                rsum[g] += (e[g * 4 + 0] + e[g * 4 + 1]) + (e[g * 4 + 2] + e[g * 4 + 3]);
#pragma unroll
            for (int k1 = 0; k1 < 2; k1++) {
                unsigned int u01 = __builtin_bit_cast(unsigned int,
                    __builtin_amdgcn_cvt_pkrtz(e[k1 * 8 + 0], e[k1 * 8 + 1]));
                unsigned int u23 = __builtin_bit_cast(unsigned int,
                    __builtin_amdgcn_cvt_pkrtz(e[k1 * 8 + 2], e[k1 * 8 + 3]));
                unsigned int w01 = __builtin_bit_cast(unsigned int,
                    __builtin_amdgcn_cvt_pkrtz(e[k1 * 8 + 4], e[k1 * 8 + 5]));
                unsigned int w23 = __builtin_bit_cast(unsigned int,
                    __builtin_amdgcn_cvt_pkrtz(e[k1 * 8 + 6], e[k1 * 8 + 7]));
                asm("v_permlane32_swap_b32 %0, %1" : "+v"(u01), "+v"(w01));
                asm("v_permlane32_swap_b32 %0, %1" : "+v"(u23), "+v"(w23));
                uint4v p; p[0] = u01; p[1] = u23; p[2] = w01; p[3] = w23;
                pbA[lblk * 2 + k1] = __builtin_bit_cast(half8, p);
            }
        }

        half8 vabB[8];
#pragma unroll
        for (int c = 0; c < 8; c++) vabB[c] = *(const half8*)(baseB + (8 + c) * 512 + lane * 8);

        // PV_A
        __builtin_amdgcn_s_setprio(1);
#pragma unroll
        for (int dblk = 0; dblk < 2; dblk++)
#pragma unroll
            for (int ks = 0; ks < 4; ks++)
                oacc[dblk] = __builtin_amdgcn_mfma_f32_32x32x16_f16(
                    vabA[dblk * 4 + ks], pbA[ks], oacc[dblk], 0, 0, 0);
        __builtin_amdgcn_s_setprio(0);

        // exp_B -> pbB (VALU under PV_A's matrix time)
        half8 pbB[4];
#pragma unroll
        for (int lblk = 0; lblk < 2; lblk++) {
            float e[16];
#pragma unroll
            for (int r = 0; r < 16; r++) e[r] = __builtin_amdgcn_exp2f(sttB[lblk][r]);
#pragma unroll
            for (int g = 0; g < 4; g++)
                rsum[g] += (e[g * 4 + 0] + e[g * 4 + 1]) + (e[g * 4 + 2] + e[g * 4 + 3]);
#pragma unroll
            for (int k1 = 0; k1 < 2; k1++) {
                unsigned int u01 = __builtin_bit_cast(unsigned int,
                    __builtin_amdgcn_cvt_pkrtz(e[k1 * 8 + 0], e[k1 * 8 + 1]));
                unsigned int u23 = __builtin_bit_cast(unsigned int,
                    __builtin_amdgcn_cvt_pkrtz(e[k1 * 8 + 2], e[k1 * 8 + 3]));
                unsigned int w01 = __builtin_bit_cast(unsigned int,
                    __builtin_amdgcn_cvt_pkrtz(e[k1 * 8 + 4], e[k1 * 8 + 5]));
                unsigned int w23 = __builtin_bit_cast(unsigned int,
                    __builtin_amdgcn_cvt_pkrtz(e[k1 * 8 + 6], e[k1 * 8 + 7]));
                asm("v_permlane32_swap_b32 %0, %1" : "+v"(u01), "+v"(w01));
                asm("v_permlane32_swap_b32 %0, %1" : "+v"(u23), "+v"(w23));
                uint4v p; p[0] = u01; p[1] = u23; p[2] = w01; p[3] = w23;
                pbB[lblk * 2 + k1] = __builtin_bit_cast(half8, p);
            }
        }

        // PV_B
        __builtin_amdgcn_s_setprio(1);
#pragma unroll
        for (int dblk = 0; dblk < 2; dblk++)
#pragma unroll
            for (int ks = 0; ks < 4; ks++)
                oacc[dblk] = __builtin_amdgcn_mfma_f32_32x32x16_f16(
                    vabB[dblk * 4 + ks], pbB[ks], oacc[dblk], 0, 0, 0);
        __builtin_amdgcn_s_setprio(0);

        __syncthreads();   // drains next-tile glds; protects buf reuse
    }

    // ---- denominator: pair-combine own+partner (lane<->lane+32) ----
    float rs = (rsum[0] + rsum[1]) + (rsum[2] + rsum[3]);
    unsigned int ra = __builtin_bit_cast(unsigned int, rs);
    unsigned int rb = ra;
    asm("" : "+v"(rb));   // force distinct register lineage
    asm("v_permlane32_swap_b32 %0, %1" : "+v"(ra), "+v"(rb));
    const float inv = 1.0f / (__builtin_bit_cast(float, ra) + __builtin_bit_cast(float, rb));
    const int s = s0 + ln;

    if (L < NL - 1) {
#pragma unroll
        for (int dblk = 0; dblk < 2; dblk++)
#pragma unroll
            for (int q2 = 0; q2 < 4; q2++) {
                half4 hv;
#pragma unroll
                for (int r = 0; r < 4; r++) hv[r] = (_Float16)(oacc[dblk][q2 * 4 + r] * inv);
                *(half4*)(xout + (((size_t)((b << 10) + s)) << 8) +
                          (h << 6) + dblk * 32 + q2 * 8 + hi * 4) = hv;
            }
    } else if (isbf_final) {
#pragma unroll
        for (int dblk = 0; dblk < 2; dblk++)
#pragma unroll
            for (int q2 = 0; q2 < 4; q2++)
#pragma unroll
                for (int r = 0; r < 4; r++) {
                    const int c = (h << 6) + dblk * 32 + q2 * 8 + hi * 4 + r;
                    ((unsigned short*)outp)[(((size_t)(b * CD + c)) << 10) + s] =
                        f2bf(oacc[dblk][q2 * 4 + r] * inv);
                }
    } else {
#pragma unroll
        for (int dblk = 0; dblk < 2; dblk++)
#pragma unroll
            for (int q2 = 0; q2 < 4; q2++)
#pragma unroll
                for (int r = 0; r < 4; r++) {
                    const int c = (h << 6) + dblk * 32 + q2 * 8 + hi * 4 + r;
                    ((float*)outp)[(((size_t)(b * CD + c)) << 10) + s] =
                        oacc[dblk][q2 * 4 + r] * inv;
                }
    }
}

extern "C" void kernel_launch(void* const* d_in, const int* in_sizes, int n_in,
                              void* d_out, int out_size, void* d_ws, size_t ws_size,
                              hipStream_t stream) {
    const void* xin = d_in[0];
    // d_in[1] = length: used only for its shape (L=1024) — values irrelevant
    const void* win = d_in[2];
    const void* kvin = d_in[3];

    char* ws = (char*)d_ws;
    const size_t MB = 1u << 20;
    _Float16* xa  = (_Float16*)(ws);               // 8 MB  (B,S,C) f16
    _Float16* xb  = (_Float16*)(ws + 8 * MB);      // 8 MB  ping-pong
    _Float16* w16 = (_Float16*)(ws + 16 * MB);     // 0.5 MB
    _Float16* kaF = (_Float16*)(ws + 17 * MB);     // 2 MB  K fragment-order
    _Float16* vtF = (_Float16*)(ws + 19 * MB);     // 2 MB  V^T fragment-order
    int*      flg = (int*)(ws + 21 * MB);          // dtype flag

    prep_all<<<dim3(1024 + 256 + 128), 256, 0, stream>>>(xin, win, kvin, xa, w16, kaF, vtF, flg);

    _Float16* cur = xa;
    _Float16* nxt = xb;
    for (int i = 0; i < NL; i++) {
        layer_fused<<<dim3(SQL / 128, NH, BB), 256, 0, stream>>>(cur, nxt, w16, kaF, vtF,
                                                                 flg, d_out, i);
        _Float16* tmp = cur; cur = nxt; nxt = tmp;
    }
}